// Round 8
// baseline (150.756 us; speedup 1.0000x reference)
//
#include <hip/hip_runtime.h>

// filtered_lrelu: 2x FIR up (12 taps) -> lrelu(0.01) -> 2x FIR down (12 taps)
// x: [8,128,130,130] f32, filters: 12 f32, out: [8,128,128,128] f32.
//
// v9 = v8 with the stage-A pipeline WAR bug fixed: consume slot k into locals
// BEFORE issuing LOADR(k+3) (depth-3 %3 slots collide otherwise: (k+3)%3==k%3,
// so the prefetch overwrote the data round k was about to consume).
//
// Structure: tile 32x64, UST=76, 22496 B LDS, 7 blocks/CU, pk-f32 math,
// symmetric-filter SGPR coeffs, x4 gain at store, explicit latency hiding:
//   - stage A: branchless row clamp; depth-3 global-load pipeline.
//   - stage B: depth-3 LDS prefetch via 3-name rotating regs (nA/nB/nC).
//   - stage C: all 18 v2f loads issued before any compute.

typedef float v2f __attribute__((ext_vector_type(2)));

#define TOX 32
#define TOY 64
#define UST 76          // u/w row stride (floats); non-pow2 => bank spread
#define U_ROWS 74       // TOY + 10

#define VFMA(a, b, c) __builtin_elementwise_fma((a), (b), (c))
#define VMAX(a, b)    __builtin_elementwise_max((a), (b))

__device__ __forceinline__ v2f vsp(float s) { return (v2f){s, s}; }

template <bool COLSAFE>
__device__ __forceinline__ void stage_a(const float* __restrict__ xc,
                                        float* __restrict__ u_sh,
                                        float e0, float e1, float e2,
                                        float e3, float e4, float e5,
                                        int tid, int ox0, int oy0) {
    const int g   = tid % 19;
    const int h0  = tid / 19;            // 0..12 for tid<247
    const int gc0 = ox0 - 4 + 2 * g;
    bool c0 = true, c2 = true, c4 = true, c6 = true;
    int  o0 = gc0, o2 = gc0 + 2, o4 = gc0 + 4, o6 = gc0 + 6;
    if (!COLSAFE) {
        c0 = (unsigned)(gc0    ) <= 128u; o0 = c0 ? gc0     : 0;
        c2 = (unsigned)(gc0 + 2) <= 128u; o2 = c2 ? gc0 + 2 : 0;
        c4 = (unsigned)(gc0 + 4) <= 128u; o4 = c4 ? gc0 + 4 : 0;
        c6 = (unsigned)(gc0 + 6) <= 129u; o6 = c6 ? gc0 + 6 : 0;
    }
    if (tid < 247) {
        // Branchless row offsets + validity for all 6 rounds (h=h0+13k).
        int  gofs[6];
        bool rok[6];
#pragma unroll
        for (int k = 0; k < 6; ++k) {
            const int gr = oy0 - 4 + h0 + 13 * k;
            rok[k]  = ((unsigned)gr < 130u);
            gofs[k] = (rok[k] ? gr : 0) * 130;
        }
        // Depth-3 load pipeline; slots constant-indexed (fully unrolled).
        float2 a01[3], a23[3], a45[3];
        float  a6[3];
#define LOADR(k)                                                               \
        { const float* __restrict__ xr = xc + gofs[k];                         \
          a01[(k) % 3] = *(const float2*)(xr + o0);                            \
          a23[(k) % 3] = *(const float2*)(xr + o2);                            \
          a45[(k) % 3] = *(const float2*)(xr + o4);                            \
          a6 [(k) % 3] = xr[o6]; }
        LOADR(0) LOADR(1) LOADR(2)
#pragma unroll
        for (int k = 0; k < 6; ++k) {
            // CONSUME slot k first (waits on loads issued 3 rounds back)...
            float s0 = a01[k % 3].x, s1 = a01[k % 3].y,
                  s2 = a23[k % 3].x, s3 = a23[k % 3].y,
                  s4 = a45[k % 3].x, s5 = a45[k % 3].y, s6 = a6[k % 3];
            // ...THEN reuse the slot for round k+3's prefetch (WAR-safe).
            if (k + 3 < 6) LOADR(k + 3)
            if (!COLSAFE) {
                s0 = c0 ? s0 : 0.f; s1 = c0 ? s1 : 0.f;
                s2 = c2 ? s2 : 0.f; s3 = c2 ? s3 : 0.f;
                s4 = c4 ? s4 : 0.f; s5 = c4 ? s5 : 0.f;
                s6 = c6 ? s6 : 0.f;
            }
            // symmetric filter: odd-phase coeffs are e5..e0 reversed
            float u0 = e0*s5 + e1*s4 + e2*s3 + e3*s2 + e4*s1 + e5*s0;
            float u1 = e5*s5 + e4*s4 + e3*s3 + e2*s2 + e1*s1 + e0*s0;
            float u2 = e0*s6 + e1*s5 + e2*s4 + e3*s3 + e4*s2 + e5*s1;
            float u3 = e5*s6 + e4*s5 + e3*s4 + e2*s3 + e1*s2 + e0*s1;
            if (!rok[k]) { u0 = 0.f; u1 = 0.f; u2 = 0.f; u3 = 0.f; }
            const int h = h0 + 13 * k;
            if (k < 5 || h < U_ROWS)     // write guard only; loads were safe
                *(float4*)(u_sh + h * UST + 4 * g) = make_float4(u0, u1, u2, u3);
        }
#undef LOADR
    }
}

__global__ __launch_bounds__(256, 7)
void flrelu_fused_kernel(const float* __restrict__ x,
                         const float* __restrict__ upf,
                         const float* __restrict__ downf,
                         float* __restrict__ out) {
    __shared__ __align__(16) float u_s[U_ROWS * UST];   // 22496 B

    const int tid = threadIdx.x;
    const int ch  = blockIdx.z;
    const int ox0 = blockIdx.x * TOX;
    const int oy0 = blockIdx.y * TOY;

    // Symmetric 12-tap filters: 6 unique coeffs each (uniform -> SGPR).
    const float e0 = upf[0],   e1 = upf[2],   e2 = upf[4],
                e3 = upf[6],   e4 = upf[8],   e5 = upf[10];
    const float d0 = downf[0], d1 = downf[1], d2 = downf[2],
                d3 = downf[3], d4 = downf[4], d5 = downf[5];

    // ---- stage A: global -> u (horizontal up-conv, raw gain), rows 0..73 ----
    {
        const float* __restrict__ xc = x + (size_t)ch * (130 * 130);
        if (ox0 == 0 || ox0 + TOX == 128)
            stage_a<false>(xc, u_s, e0, e1, e2, e3, e4, e5, tid, ox0, oy0);
        else
            stage_a<true>(xc, u_s, e0, e1, e2, e3, e4, e5, tid, ox0, oy0);
    }
    __syncthreads();

    // ---- stage B: vert up + lrelu + vert down, packed column-pairs ----
    // 76 tasks (2 waves): seg = tid>=38 (32 out rows each), pair p = 0..37.
    // 37 macro-unrolled steps; depth-3 LDS prefetch (nA/nB/nC, period 3):
    // STEP(m) consumes the value loaded at step m-3 (row m+5), prefetches
    // row m+8. w ALIASES u as v5/v7: seg0 w rows 0..31 -> slots 0..31
    // (disjoint from seg1 reads 32..73); seg1 w rows -> slots 42..73
    // (disjoint from seg0 reads 0..41). Pair-columns thread-private; the
    // seg1 prefetch of slot s (step s-40) precedes its aliased write
    // (step s-37) in same-thread program order.
    if (tid < 76) {
        const int seg = (tid >= 38) ? 1 : 0;
        const int p   = tid - 38 * seg;
        const float* ucol = u_s + (seg * 32) * UST + 2 * p;
        float*       wout = u_s + (seg * 42) * UST + 2 * p;
        v2f rA = *(const v2f*)(ucol + 0*UST), rB = *(const v2f*)(ucol + 1*UST),
            rC = *(const v2f*)(ucol + 2*UST), rD = *(const v2f*)(ucol + 3*UST),
            rE = *(const v2f*)(ucol + 4*UST), rF;
        v2f nA = *(const v2f*)(ucol + 5*UST),
            nB = *(const v2f*)(ucol + 6*UST),
            nC = *(const v2f*)(ucol + 7*UST);
        v2f wA = vsp(0.f), wB = vsp(0.f), wC = vsp(0.f),
            wD = vsp(0.f), wE = vsp(0.f), wF = vsp(0.f);

        // STEP(m): consume prefetched row m+5 (n0_), prefetch row m+8 into
        // n0_ (becomes n2 next step), compute z/lrelu, accumulate w, retire.
#define STEP(m, r0_,r1_,r2_,r3_,r4_,r5_, n0_,n1_,n2_, w0_,w1_,w2_,w3_,w4_,w5_) \
        {                                                                      \
            r5_ = n0_;                                                         \
            if ((m) + 8 <= 41)                                                 \
                n0_ = *(const v2f*)(ucol + ((m) + 8) * UST);                   \
            v2f z0 = VFMA(vsp(e0), r5_, VFMA(vsp(e1), r4_, VFMA(vsp(e2), r3_, \
                     VFMA(vsp(e3), r2_, VFMA(vsp(e4), r1_, vsp(e5)*r0_)))));   \
            v2f z1 = VFMA(vsp(e5), r5_, VFMA(vsp(e4), r4_, VFMA(vsp(e3), r3_, \
                     VFMA(vsp(e2), r2_, VFMA(vsp(e1), r1_, vsp(e0)*r0_)))));   \
            z0 = VMAX(z0, 0.01f * z0);                                         \
            z1 = VMAX(z1, 0.01f * z1);                                         \
            w0_ = VFMA(vsp(d0), z0, vsp(d1) * z1);                             \
            w1_ = VFMA(vsp(d2), z0, VFMA(vsp(d3), z1, w1_));                   \
            w2_ = VFMA(vsp(d4), z0, VFMA(vsp(d5), z1, w2_));                   \
            w3_ = VFMA(vsp(d5), z0, VFMA(vsp(d4), z1, w3_));                   \
            w4_ = VFMA(vsp(d3), z0, VFMA(vsp(d2), z1, w4_));                   \
            w5_ = VFMA(vsp(d1), z0, VFMA(vsp(d0), z1, w5_));                   \
            if ((m) >= 5) *(v2f*)(wout + ((m) - 5) * UST) = w5_;               \
        }
#define S6(m0)                                                                 \
        STEP(m0+0, rA,rB,rC,rD,rE,rF, nA,nB,nC, wA,wF,wE,wD,wC,wB)             \
        STEP(m0+1, rB,rC,rD,rE,rF,rA, nB,nC,nA, wB,wA,wF,wE,wD,wC)             \
        STEP(m0+2, rC,rD,rE,rF,rA,rB, nC,nA,nB, wC,wB,wA,wF,wE,wD)             \
        STEP(m0+3, rD,rE,rF,rA,rB,rC, nA,nB,nC, wD,wC,wB,wA,wF,wE)             \
        STEP(m0+4, rE,rF,rA,rB,rC,rD, nB,nC,nA, wE,wD,wC,wB,wA,wF)             \
        STEP(m0+5, rF,rA,rB,rC,rD,rE, nC,nA,nB, wF,wE,wD,wC,wB,wA)

        S6(0) S6(6) S6(12) S6(18) S6(24) S6(30)
        STEP(36, rA,rB,rC,rD,rE,rF, nA,nB,nC, wA,wF,wE,wD,wC,wB)
#undef S6
#undef STEP
    }
    __syncthreads();

    // ---- stage C: horizontal down-conv (packed phase-pairs) -> out 32x64 ----
    // oy = {t, 32+t}, g = tid&7; ALL 18 v2f loads issued before any compute.
    {
        const int g = tid & 7;
        const int t = tid >> 3;
        const v2f D01 = {d0, d1}, D23 = {d2, d3}, D45 = {d4, d5},
                  D54 = {d5, d4}, D32 = {d3, d2}, D10 = {d1, d0};
        float* __restrict__ outc = out + (size_t)ch * (128 * 128);
        const float* wr0 = u_s + t * UST + 8 * g;              // w row t
        const float* wr1 = u_s + (42 + t) * UST + 8 * g;       // w row 32+t
        v2f a0 = *(const v2f*)(wr0 + 0),  a1 = *(const v2f*)(wr0 + 2),
            a2 = *(const v2f*)(wr0 + 4),  a3 = *(const v2f*)(wr0 + 6),
            a4 = *(const v2f*)(wr0 + 8),  a5 = *(const v2f*)(wr0 + 10),
            a6 = *(const v2f*)(wr0 + 12), a7 = *(const v2f*)(wr0 + 14),
            a8 = *(const v2f*)(wr0 + 16);
        v2f b0 = *(const v2f*)(wr1 + 0),  b1 = *(const v2f*)(wr1 + 2),
            b2 = *(const v2f*)(wr1 + 4),  b3 = *(const v2f*)(wr1 + 6),
            b4 = *(const v2f*)(wr1 + 8),  b5 = *(const v2f*)(wr1 + 10),
            b6 = *(const v2f*)(wr1 + 12), b7 = *(const v2f*)(wr1 + 14),
            b8 = *(const v2f*)(wr1 + 16);
        {
            v2f P0 = VFMA(D01,a0, VFMA(D23,a1, VFMA(D45,a2,
                     VFMA(D54,a3, VFMA(D32,a4, D10*a5)))));
            v2f P1 = VFMA(D01,a1, VFMA(D23,a2, VFMA(D45,a3,
                     VFMA(D54,a4, VFMA(D32,a5, D10*a6)))));
            v2f P2 = VFMA(D01,a2, VFMA(D23,a3, VFMA(D45,a4,
                     VFMA(D54,a5, VFMA(D32,a6, D10*a7)))));
            v2f P3 = VFMA(D01,a3, VFMA(D23,a4, VFMA(D45,a5,
                     VFMA(D54,a6, VFMA(D32,a7, D10*a8)))));
            *(float4*)(outc + (size_t)(oy0 + t) * 128 + ox0 + 4 * g) =
                make_float4(4.0f * (P0.x + P0.y), 4.0f * (P1.x + P1.y),
                            4.0f * (P2.x + P2.y), 4.0f * (P3.x + P3.y));
        }
        {
            v2f P0 = VFMA(D01,b0, VFMA(D23,b1, VFMA(D45,b2,
                     VFMA(D54,b3, VFMA(D32,b4, D10*b5)))));
            v2f P1 = VFMA(D01,b1, VFMA(D23,b2, VFMA(D45,b3,
                     VFMA(D54,b4, VFMA(D32,b5, D10*b6)))));
            v2f P2 = VFMA(D01,b2, VFMA(D23,b3, VFMA(D45,b4,
                     VFMA(D54,b5, VFMA(D32,b6, D10*b7)))));
            v2f P3 = VFMA(D01,b3, VFMA(D23,b4, VFMA(D45,b5,
                     VFMA(D54,b6, VFMA(D32,b7, D10*b8)))));
            *(float4*)(outc + (size_t)(oy0 + 32 + t) * 128 + ox0 + 4 * g) =
                make_float4(4.0f * (P0.x + P0.y), 4.0f * (P1.x + P1.y),
                            4.0f * (P2.x + P2.y), 4.0f * (P3.x + P3.y));
        }
    }
}

extern "C" void kernel_launch(void* const* d_in, const int* in_sizes, int n_in,
                              void* d_out, int out_size, void* d_ws, size_t ws_size,
                              hipStream_t stream) {
    const float* x     = (const float*)d_in[0];
    const float* upf   = (const float*)d_in[1];
    const float* downf = (const float*)d_in[2];
    float* out = (float*)d_out;

    dim3 grid(128 / TOX, 128 / TOY, 8 * 128);   // 4 x 2 x 1024
    dim3 block(256);
    flrelu_fused_kernel<<<grid, block, 0, stream>>>(x, upf, downf, out);
}